// Round 1
// 289.114 us; speedup vs baseline: 1.0927x; 1.0927x over previous
//
#include <hip/hip_runtime.h>
#include <stdint.h>

// LSTM autoencoder B=32768 T=30 I=4 H=64 L=32, fp32 in/out.
// v14 = v13 (316us bench / 259us rocprof) + three VALU cuts:
//  1. MFMA operand swap: A=weights, B=data (A/B frag layouts are identical on
//     gfx950, m120, so staging is unchanged). C/D rows are now UNITS
//     (quad*4+r), cols BATCH (lane&15) -> each lane's 4 h outputs per tile are
//     k-contiguous in the next step's B-fragment: epilogue packs them with
//     2x v_cvt_pk_bf16_f32 + one ds_write_b64 (contiguous 512B per write,
//     conflict-free). Was: 4x f2bf + 4x scalar ds_write_b16, 4-8-way conflicts
//     (SQ_LDS_BANK_CONFLICT 6.9M). Biases now init C via one ds_read_b128.
//  2. Activation rcp-merge (exact algebra): i*g=(eg-1)/((1+ei)(1+eg)),
//     c=[c*Z+(eg-1)*X]*rcp(X*Z); h=(ec-1)*rcp((1+eo)(1+ec)).
//     7 transcendentals/unit (5 exp2 + 2 rcp), was 10.
//  3. x-fold fragment built in registers (cvt_pk + cndmask); xfold LDS
//     round-trip + its WB removed.
// Structure unchanged: layer-pipelined, 16 waves/block (1024 thr), 8 pairs x
// 16 batches, grid 256, 4 waves/SIMD. log2e folded into weights at staging
// (gate rows i,f,o scaled log2e, g rows 2*log2e); raw v_exp_f32 = exp2.
// Layouts (HW-verified): C/D col=lane&15,row=(lane>>4)*4+reg [m89];
// A m=lane&15,k=(lane>>4)*8+j [m120]; B n=lane&15,k=(lane>>4)*8+j.

typedef unsigned short u16;
typedef unsigned int u32;
typedef __attribute__((ext_vector_type(8))) short bf16x8;
typedef __attribute__((ext_vector_type(4))) float f32x4;
typedef __attribute__((ext_vector_type(4))) u32 u32x4;
typedef __attribute__((ext_vector_type(2))) u32 u32x2;

#define BATCH 32768
#define TT 30
#define IN 4
#define WAVES 16
#define BLOCKT (WAVES * 64)   // 1024
#define MB 16
#define NPAIR 8
#define BPB (NPAIR * MB)      // 128 batches/block -> grid 256, 1 round

#define LOG2E 1.4426950408889634f
#define LOG2E2 2.8853900817779268f

// ---- LDS word (u32/float) offsets ----
#define WREG 18432
// enc phase
#define O_WHH1HI 0       // 8192 words (32 frags)
#define O_W1FOLD 8192    // 4096 words (16 frags: x+bias fold tile)
#define O_WIH2HI 12288   // 4096
#define O_WHH2HI 16384   // 2048 -> 18432
// dec phase (same region)
#define O_WHH3HI 0       // 8192
#define O_WIH3HI 8192    // 4096
#define O_WIH4HI 12288   // 512
#define O_W4HHF  12800   // 64 fp32 -> 12864

#define NBIAS 400   // b2[128] @0 | b3[256] @128 | b4[16] @384
// per-pair floats: h1/h3 dbuf 1024 (2 x 512) | h2 256 | gbuf 256 | h4 64
#define PBUF 1600
#define SMEM_WORDS (WREG + NBIAS + NPAIR * PBUF)   // 31632
#define SMEM_BYTES (SMEM_WORDS * 4)                // 126528 <= 163840

#define WB() __builtin_amdgcn_wave_barrier()
// NOTE arg order: A = weight frag, B = data frag (operand swap vs v13).
#define MFMA(a, b, c) __builtin_amdgcn_mfma_f32_16x16x32_bf16((a), (b), (c), 0, 0, 0)

__device__ __forceinline__ u16 f2bf(float f) {   // RNE fp32->bf16 (staging)
    u32 u = __float_as_uint(f);
    u += 0x7fffu + ((u >> 16) & 1u);
    return (u16)(u >> 16);
}
__device__ __forceinline__ float bf2f(u16 v) { return __uint_as_float(((u32)v) << 16); }

// packed RNE fp32x2 -> bf16x2 (lo=a, hi=b). Guide-verified mnemonic (T12).
__device__ __forceinline__ u32 cvtpk2(float a, float b) {
    u32 d;
    asm("v_cvt_pk_bf16_f32 %0, %1, %2" : "=v"(d) : "v"(a), "v"(b));
    return d;
}

// Fused LSTM cell update. Inputs pre-scaled (i,f,o by log2e; g by 2*log2e).
// Exact algebra of sig/tanh with merged reciprocals: 5 exp2 + 2 rcp.
__device__ __forceinline__ float unitH(float yi, float yf, float yg, float yo, float& c) {
    const float ei = __builtin_amdgcn_exp2f(-yi);
    const float ef = __builtin_amdgcn_exp2f(-yf);
    const float eg = __builtin_amdgcn_exp2f(yg);
    const float eo = __builtin_amdgcn_exp2f(-yo);
    const float Z = (1.f + ei) * (1.f + eg);
    const float X = 1.f + ef;
    const float num = fmaf(eg - 1.f, X, c * Z);
    c = num * __builtin_amdgcn_rcpf(X * Z);
    const float ec = __builtin_amdgcn_exp2f(c * LOG2E2);
    return (ec - 1.f) * __builtin_amdgcn_rcpf((1.f + eo) * (1.f + ec));
}

// Stage fp32 W[N][K] -> bf16 hi, operand-fragment order, rows pre-scaled by
// gate factor (gate = (n>>GS)&3; g-gate (==2) gets 2*log2e, else log2e).
// u16 idx = ((nt*KT + kt)*64 + l)*8 + j, n = nt*16+(l&15), k = kt*32+((l>>4)<<3)+j
template <int KT, int GS>
__device__ __forceinline__ void stageBh(u16* hi, const float* src, int N, int tid) {
    const int K = KT * 32;
    const int total = N * K;
    for (int idx = tid; idx < total; idx += BLOCKT) {
        const int j = idx & 7;
        const int l = (idx >> 3) & 63;
        const int pr = idx >> 9;
        const int kt = pr & (KT - 1);
        const int nt = pr / KT;
        const int n = (nt << 4) | (l & 15);
        const int k = (kt << 5) + ((l >> 4) << 3) + j;
        const float s = (((n >> GS) & 3) == 2) ? LOG2E2 : LOG2E;
        hi[idx] = f2bf(src[n * K + k] * s);
    }
}

__global__ __launch_bounds__(BLOCKT)
__attribute__((amdgpu_waves_per_eu(4, 4)))
void lstm_ae(
    const float* __restrict__ x,
    const float* __restrict__ w1ih, const float* __restrict__ w1hh,
    const float* __restrict__ b1i, const float* __restrict__ b1h,
    const float* __restrict__ w2ih, const float* __restrict__ w2hh,
    const float* __restrict__ b2i, const float* __restrict__ b2h,
    const float* __restrict__ w3ih, const float* __restrict__ w3hh,
    const float* __restrict__ b3i, const float* __restrict__ b3h,
    const float* __restrict__ w4ih, const float* __restrict__ w4hh,
    const float* __restrict__ b4i, const float* __restrict__ b4h,
    float* __restrict__ out) {
    extern __shared__ float smem[];
    float* W = smem;
    float* biasF = smem + WREG;        // b2[128] b3[256] b4[16] (pre-scaled)
    float* bufs = biasF + NBIAS;

    const int tid = threadIdx.x;
    const int wave = tid >> 6, lane = tid & 63;
    const int pair = wave & 7, role = wave >> 3;   // 0=front(enc1/dec1) 1=back(enc2/dec2)
    const int col = lane & 15, quad = lane >> 4;

    float* pb = bufs + pair * PBUF;
    u16* h1d = (u16*)pb;               // 2048 u16: dbuf parity p at p*1024
    u16* h2b = (u16*)(pb + 1024);      // 512 u16 (h2/latent, 1 k-tile)
    float* gbuf = pb + 1280;           // [16 batch][16 gate] fp32 (back, dec)
    float* bufH4 = pb + 1536;          // [16 batch][4] fp32 (back, dec)

    const int b0w = blockIdx.x * BPB + pair * MB;
    // per-lane u16 offset base of a lane's 4-unit group inside a k-tile frag:
    // off(q) = hbase + (q-dependent frag offsets); 4 consecutive u16 = b64.
    const int hbase = (col << 3) + ((quad & 1) << 2) + ((quad >> 1) << 7);

    // ---------------- stage ENCODER weights + biases (pre-scaled) ----------------
    stageBh<2, 6>((u16*)(W + O_WHH1HI), w1hh, 256, tid);
    stageBh<2, 5>((u16*)(W + O_WIH2HI), w2ih, 128, tid);
    stageBh<1, 5>((u16*)(W + O_WHH2HI), w2hh, 128, tid);
    // fold tile (weight side): k0-3 whi | k4-7 whi | k8-11 wlo | k12 b_hi | k13 b_lo
    {
        u16* F = (u16*)(W + O_W1FOLD);
        for (int idx = tid; idx < 16 * 512; idx += BLOCKT) {
            const int nt = idx >> 9;
            const int rem = idx & 511;
            const int l = rem >> 3;
            const int j = rem & 7;
            const int q = l >> 4;
            const int n = (nt << 4) | (l & 15);
            const float s = ((n >> 6) == 2) ? LOG2E2 : LOG2E;
            u16 v = 0;
            if (q == 0) {
                v = f2bf(w1ih[n * 4 + (j & 3)] * s);
            } else if (q == 1) {
                if (j < 4) {
                    const float w = w1ih[n * 4 + j] * s;
                    v = f2bf(w - bf2f(f2bf(w)));
                } else if (j == 4) {
                    v = f2bf((b1i[n] + b1h[n]) * s);
                } else if (j == 5) {
                    const float b = (b1i[n] + b1h[n]) * s;
                    v = f2bf(b - bf2f(f2bf(b)));
                }
            }
            F[idx] = v;
        }
    }
    for (int i = tid; i < 128; i += BLOCKT)
        biasF[i] = (b2i[i] + b2h[i]) * ((((i >> 5) & 3) == 2) ? LOG2E2 : LOG2E);
    for (int i = tid; i < 256; i += BLOCKT)
        biasF[128 + i] = (b3i[i] + b3h[i]) * ((((i >> 6) & 3) == 2) ? LOG2E2 : LOG2E);
    for (int i = tid; i < 16; i += BLOCKT)
        biasF[384 + i] = (b4i[i] + b4h[i]) * ((((i >> 2) & 3) == 2) ? LOG2E2 : LOG2E);
    // zero pair buffers
    {
        u32* z = (u32*)pb;
        if (role == 0) {
            for (int i = lane; i < 1024; i += 64) z[i] = 0u;   // h1 dbuf
        } else {
            for (int i = lane; i < 256; i += 64) z[1024 + i] = 0u;   // h2
            bufH4[lane] = 0.f;
        }
    }
    __syncthreads();

    const u16* Whh1hi = (const u16*)(W + O_WHH1HI);
    const u16* W1fold = (const u16*)(W + O_W1FOLD);
    const u16* Wih2hi = (const u16*)(W + O_WIH2HI);
    const u16* Whh2hi = (const u16*)(W + O_WHH2HI);

    // ================= encoder (pipelined) =================
    // c-state mapping (post-swap): c[q][r] <-> (batch=col, unit=q*16+quad*4+r)
    float c1[4][4];
    float c2[2][4];
#pragma unroll
    for (int q = 0; q < 4; ++q)
#pragma unroll
        for (int r = 0; r < 4; ++r) c1[q][r] = 0.f;
#pragma unroll
    for (int q = 0; q < 2; ++q)
#pragma unroll
        for (int r = 0; r < 4; ++r) c2[q][r] = 0.f;

    const f32x4 zf = {0.f, 0.f, 0.f, 0.f};
    float4 xcur;
    if (role == 0)
        xcur = *reinterpret_cast<const float4*>(x + ((size_t)(b0w + col) * TT + 0) * IN);

    for (int s = 0; s <= TT; ++s) {
        if (role == 0) {
            if (s < TT) {
                // ---- front: enc1 for t=s ----
                // x B-frag built in registers: quad0 = [xhi, xlo], quad1 =
                // [xhi, 1.0 1.0 0 0] (bias rows), quad2/3 = 0 (weight rows 0).
                const u32 hi01 = cvtpk2(xcur.x, xcur.y);
                const u32 hi23 = cvtpk2(xcur.z, xcur.w);
                const float r0 = xcur.x - __uint_as_float(hi01 << 16);
                const float r1 = xcur.y - __uint_as_float(hi01 & 0xffff0000u);
                const float r2 = xcur.z - __uint_as_float(hi23 << 16);
                const float r3 = xcur.w - __uint_as_float(hi23 & 0xffff0000u);
                const u32 lo01 = cvtpk2(r0, r1);
                const u32 lo23 = cvtpk2(r2, r3);
                u32x4 xv;
                xv.x = (quad <= 1) ? hi01 : 0u;
                xv.y = (quad <= 1) ? hi23 : 0u;
                xv.z = (quad == 0) ? lo01 : ((quad == 1) ? 0x3F803F80u : 0u);
                xv.w = (quad == 0) ? lo23 : 0u;
                const bf16x8 a1x = __builtin_bit_cast(bf16x8, xv);
                {   // prefetch next x
                    const int tn = (s + 1 < TT) ? s + 1 : s;
                    xcur = *reinterpret_cast<const float4*>(
                        x + ((size_t)(b0w + col) * TT + tn) * IN);
                }
                const u16* hprev = h1d + (((s + 1) & 1) << 10);   // h1[s-1]
                u16* hout = h1d + ((s & 1) << 10);                // h1[s]
                const bf16x8 a1h0 = *reinterpret_cast<const bf16x8*>(hprev + lane * 8);
                const bf16x8 a1h1 = *reinterpret_cast<const bf16x8*>(hprev + (64 + lane) * 8);
#pragma unroll
                for (int q = 0; q < 4; ++q) {   // quarter-loop: acc[4]
                    f32x4 acc[4];
#pragma unroll
                    for (int i = 0; i < 4; ++i) {
                        const int nt = i * 4 + q;
                        const bf16x8 bx = *reinterpret_cast<const bf16x8*>(W1fold + (nt * 64 + lane) * 8);
                        const bf16x8 bh0 = *reinterpret_cast<const bf16x8*>(Whh1hi + ((nt * 2 + 0) * 64 + lane) * 8);
                        const bf16x8 bh1 = *reinterpret_cast<const bf16x8*>(Whh1hi + ((nt * 2 + 1) * 64 + lane) * 8);
                        f32x4 a = MFMA(bx, a1x, zf);
                        a = MFMA(bh0, a1h0, a);
                        a = MFMA(bh1, a1h1, a);
                        acc[i] = a;
                    }
                    const float h0 = unitH(acc[0][0], acc[1][0], acc[2][0], acc[3][0], c1[q][0]);
                    const float h1 = unitH(acc[0][1], acc[1][1], acc[2][1], acc[3][1], c1[q][1]);
                    const float h2 = unitH(acc[0][2], acc[1][2], acc[2][2], acc[3][2], c1[q][2]);
                    const float h3 = unitH(acc[0][3], acc[1][3], acc[2][3], acc[3][3], c1[q][3]);
                    u32x2 wv;
                    wv.x = cvtpk2(h0, h1);
                    wv.y = cvtpk2(h2, h3);
                    *reinterpret_cast<u32x2*>(hout + hbase + ((q >> 1) << 9) + ((q & 1) << 8)) = wv;
                }
            }
        } else {
            if (s >= 1) {
                // ---- back: enc2 for t=s-1 ----
                const u16* hprev = h1d + (((s + 1) & 1) << 10);   // h1[s-1]
                const bf16x8 a1h0 = *reinterpret_cast<const bf16x8*>(hprev + lane * 8);
                const bf16x8 a1h1 = *reinterpret_cast<const bf16x8*>(hprev + (64 + lane) * 8);
                const bf16x8 a2h = *reinterpret_cast<const bf16x8*>(h2b + lane * 8);
                f32x4 acc2[8];
#pragma unroll
                for (int nt = 0; nt < 8; ++nt) {
                    const bf16x8 bh0 = *reinterpret_cast<const bf16x8*>(Wih2hi + ((nt * 2 + 0) * 64 + lane) * 8);
                    const bf16x8 bh1 = *reinterpret_cast<const bf16x8*>(Wih2hi + ((nt * 2 + 1) * 64 + lane) * 8);
                    const bf16x8 ch = *reinterpret_cast<const bf16x8*>(Whh2hi + (nt * 64 + lane) * 8);
                    f32x4 a = *reinterpret_cast<const f32x4*>(biasF + nt * 16 + (quad << 2));
                    a = MFMA(bh0, a1h0, a);
                    a = MFMA(bh1, a1h1, a);
                    a = MFMA(ch, a2h, a);
                    acc2[nt] = a;
                }
                WB();   // a2h read before h2 overwrite
#pragma unroll
                for (int q = 0; q < 2; ++q) {
                    const float h0 = unitH(acc2[q][0], acc2[2 + q][0], acc2[4 + q][0], acc2[6 + q][0], c2[q][0]);
                    const float h1 = unitH(acc2[q][1], acc2[2 + q][1], acc2[4 + q][1], acc2[6 + q][1], c2[q][1]);
                    const float h2 = unitH(acc2[q][2], acc2[2 + q][2], acc2[4 + q][2], acc2[6 + q][2], c2[q][2]);
                    const float h3 = unitH(acc2[q][3], acc2[2 + q][3], acc2[4 + q][3], acc2[6 + q][3], c2[q][3]);
                    u32x2 wv;
                    wv.x = cvtpk2(h0, h1);
                    wv.y = cvtpk2(h2, h3);
                    *reinterpret_cast<u32x2*>(h2b + hbase + (q << 8)) = wv;
                }
            }
        }
        __syncthreads();
    }
    // h2b holds the latent.

    // ---------------- re-stage DECODER weights (pre-scaled) ----------------
    stageBh<2, 6>((u16*)(W + O_WHH3HI), w3hh, 256, tid);
    stageBh<1, 6>((u16*)(W + O_WIH3HI), w3ih, 256, tid);
    stageBh<2, 2>((u16*)(W + O_WIH4HI), w4ih, 16, tid);
    for (int i = tid; i < 64; i += BLOCKT)
        W[O_W4HHF + i] = w4hh[i] * ((((i >> 4) & 3) == 2) ? LOG2E2 : LOG2E);
    // zero h3 dbuf (front) + h4 (back)
    if (role == 0) {
        u32* z = (u32*)pb;
        for (int i = lane; i < 1024; i += 64) z[i] = 0u;
    } else {
        bufH4[lane] = 0.f;
    }
    __syncthreads();

    const u16* Whh3hi = (const u16*)(W + O_WHH3HI);
    const u16* Wih3hi = (const u16*)(W + O_WIH3HI);
    const u16* Wih4hi = (const u16*)(W + O_WIH4HI);
    const float* W4hhF = W + O_W4HHF;

    // ================= decoder (pipelined) =================
    float c3[4][4];
    float c4 = 0.f;
    f32x4 bias4v = zf;
    bf16x8 aLh;
    if (role == 0) {
#pragma unroll
        for (int q = 0; q < 4; ++q)
#pragma unroll
            for (int r = 0; r < 4; ++r) c3[q][r] = 0.f;
        aLh = *reinterpret_cast<const bf16x8*>(h2b + lane * 8);   // latent B-frag
    } else {
        bias4v = *reinterpret_cast<const f32x4*>(biasF + 384 + (quad << 2));
    }
    const int u4 = lane & 3, mb = lane >> 2;   // back dec2 epilogue task

    for (int s = 0; s <= TT; ++s) {
        if (role == 0) {
            if (s < TT) {
                // ---- front: dec1 for t=s ----
                const u16* hprev = h1d + (((s + 1) & 1) << 10);   // h3[s-1]
                u16* hout = h1d + ((s & 1) << 10);                // h3[s]
                const bf16x8 a3h0 = *reinterpret_cast<const bf16x8*>(hprev + lane * 8);
                const bf16x8 a3h1 = *reinterpret_cast<const bf16x8*>(hprev + (64 + lane) * 8);
#pragma unroll
                for (int q = 0; q < 4; ++q) {   // quarter-loop
                    f32x4 acc[4];
#pragma unroll
                    for (int i = 0; i < 4; ++i) {
                        const int nt = i * 4 + q;
                        const bf16x8 bL = *reinterpret_cast<const bf16x8*>(Wih3hi + (nt * 64 + lane) * 8);
                        const bf16x8 bh0 = *reinterpret_cast<const bf16x8*>(Whh3hi + ((nt * 2 + 0) * 64 + lane) * 8);
                        const bf16x8 bh1 = *reinterpret_cast<const bf16x8*>(Whh3hi + ((nt * 2 + 1) * 64 + lane) * 8);
                        f32x4 a = *reinterpret_cast<const f32x4*>(biasF + 128 + nt * 16 + (quad << 2));
                        a = MFMA(bL, aLh, a);
                        a = MFMA(bh0, a3h0, a);
                        a = MFMA(bh1, a3h1, a);
                        acc[i] = a;
                    }
                    const float h0 = unitH(acc[0][0], acc[1][0], acc[2][0], acc[3][0], c3[q][0]);
                    const float h1 = unitH(acc[0][1], acc[1][1], acc[2][1], acc[3][1], c3[q][1]);
                    const float h2 = unitH(acc[0][2], acc[1][2], acc[2][2], acc[3][2], c3[q][2]);
                    const float h3 = unitH(acc[0][3], acc[1][3], acc[2][3], acc[3][3], c3[q][3]);
                    u32x2 wv;
                    wv.x = cvtpk2(h0, h1);
                    wv.y = cvtpk2(h2, h3);
                    *reinterpret_cast<u32x2*>(hout + hbase + ((q >> 1) << 9) + ((q & 1) << 8)) = wv;
                }
            }
        } else {
            if (s >= 1) {
                // ---- back: dec2 for t=s-1 ----
                const int t = s - 1;
                const u16* hprev = h1d + (((s + 1) & 1) << 10);   // h3[t]
                const bf16x8 a3h0 = *reinterpret_cast<const bf16x8*>(hprev + lane * 8);
                const bf16x8 a3h1 = *reinterpret_cast<const bf16x8*>(hprev + (64 + lane) * 8);
                f32x4 acc4 = bias4v;
                {   // fp32 Whh part: gate rows n=quad*4+r, batch col
                    const float4 hv = *reinterpret_cast<const float4*>(bufH4 + (col << 2));
#pragma unroll
                    for (int r = 0; r < 4; ++r) {
                        const float4 w4 = *reinterpret_cast<const float4*>(W4hhF + ((quad * 4 + r) << 2));
                        float sa = acc4[r];
                        sa = fmaf(w4.x, hv.x, sa);
                        sa = fmaf(w4.y, hv.y, sa);
                        sa = fmaf(w4.z, hv.z, sa);
                        sa = fmaf(w4.w, hv.w, sa);
                        acc4[r] = sa;
                    }
                }
                {
                    const bf16x8 bh0 = *reinterpret_cast<const bf16x8*>(Wih4hi + (0 * 64 + lane) * 8);
                    const bf16x8 bh1 = *reinterpret_cast<const bf16x8*>(Wih4hi + (1 * 64 + lane) * 8);
                    acc4 = MFMA(bh0, a3h0, acc4);
                    acc4 = MFMA(bh1, a3h1, acc4);
                }
                WB();
                // acc4[r] = gate-linear n=quad*4+r for batch col -> gbuf[batch][gate]
                *reinterpret_cast<f32x4*>(gbuf + (col << 4) + (quad << 2)) = acc4;
                WB();
                {   // epilogue: lane = (batch mb, unit u4)
                    const float yi = gbuf[mb * 16 + u4];
                    const float yf = gbuf[mb * 16 + 4 + u4];
                    const float yg = gbuf[mb * 16 + 8 + u4];
                    const float yo = gbuf[mb * 16 + 12 + u4];
                    const float h = unitH(yi, yf, yg, yo, c4);
                    out[((size_t)(b0w + mb) * TT + t) * IN + u4] = h;
                    bufH4[mb * 4 + u4] = h;
                }
                WB();
            }
        }
        __syncthreads();
    }
}

extern "C" void kernel_launch(void* const* d_in, const int* in_sizes, int n_in,
                              void* d_out, int out_size, void* d_ws, size_t ws_size,
                              hipStream_t stream) {
    (void)in_sizes; (void)n_in; (void)d_ws; (void)ws_size; (void)out_size;
    hipFuncSetAttribute(reinterpret_cast<const void*>(lstm_ae),
                        hipFuncAttributeMaxDynamicSharedMemorySize, SMEM_BYTES);
    const float* xi = (const float*)d_in[0];
    const float* w1ih = (const float*)d_in[1];
    const float* w1hh = (const float*)d_in[2];
    const float* b1i = (const float*)d_in[3];
    const float* b1h = (const float*)d_in[4];
    const float* w2ih = (const float*)d_in[5];
    const float* w2hh = (const float*)d_in[6];
    const float* b2i = (const float*)d_in[7];
    const float* b2h = (const float*)d_in[8];
    const float* w3ih = (const float*)d_in[9];
    const float* w3hh = (const float*)d_in[10];
    const float* b3i = (const float*)d_in[11];
    const float* b3h = (const float*)d_in[12];
    const float* w4ih = (const float*)d_in[13];
    const float* w4hh = (const float*)d_in[14];
    const float* b4i = (const float*)d_in[15];
    const float* b4h = (const float*)d_in[16];
    float* out = (float*)d_out;

    lstm_ae<<<dim3(BATCH / BPB), dim3(BLOCKT), SMEM_BYTES, stream>>>(
        xi, w1ih, w1hh, b1i, b1h, w2ih, w2hh, b2i, b2h,
        w3ih, w3hh, b3i, b3h, w4ih, w4hh, b4i, b4h, out);
}